// Round 5
// baseline (1041.712 us; speedup 1.0000x reference)
//
#include <hip/hip_runtime.h>
#include <hip/hip_cooperative_groups.h>
#include <cstdint>
#include <cstddef>

namespace cg = cooperative_groups;

#define L_ 256
#define C_ 128
#define H_ 4
#define D_ 32
#define NP_ (L_ * L_)

typedef unsigned short u16;
typedef uint32_t u32;
typedef __attribute__((ext_vector_type(8))) short bf16x8;   // 4 VGPRs: MFMA A/B frag
typedef __attribute__((ext_vector_type(4))) float f32x4;    // MFMA C/D frag

__device__ __forceinline__ float bflo(u32 u) { union { u32 i; float f; } v; v.i = u << 16; return v.f; }
__device__ __forceinline__ float bfhi(u32 u) { union { u32 i; float f; } v; v.i = u & 0xffff0000u; return v.f; }
__device__ __forceinline__ u16 f2b(float f) {
    u32 x = __float_as_uint(f);
    return (u16)((x + 0x7fffu + ((x >> 16) & 1u)) >> 16);
}
__device__ __forceinline__ u32 pk2(float lo, float hi) {
    return ((u32)f2b(hi) << 16) | (u32)f2b(lo);
}
__device__ __forceinline__ bf16x8 pack8(float4 a, float4 b) {
    union { u32 u[4]; bf16x8 v; } r;
    r.u[0] = pk2(a.x, a.y); r.u[1] = pk2(a.z, a.w);
    r.u[2] = pk2(b.x, b.y); r.u[3] = pk2(b.z, b.w);
    return r.v;
}

// ===========================================================================
// Phase bodies (round-3 verbatim, parameterized by virtual block id).
// Round-4 evidence: each kernel ~50 us with ALL pipes <20% and duration
// occupancy-insensitive; kernels sum to <=161 us vs 204-213 total ->
// >=45 us of inter-dispatch gap. This round fuses all 4 dispatches into one
// cooperative kernel with grid.sync() between phases.
// ===========================================================================

// ---- Phase 0: weight prep (vb 0..20) ----
__device__ __forceinline__ void prep_body(
    int b, int t, char* shraw,
    const float* __restrict__ Wq, const float* __restrict__ Wk, const float* __restrict__ Wv,
    const float* __restrict__ Wo, const float* __restrict__ Wg,
    const float* __restrict__ Wbias, u16* __restrict__ Wt, float* __restrict__ WbT)
{
    auto tile = reinterpret_cast<float(*)[65]>(shraw);   // [64][65] = 16640 B
    if (b < 20) {
        const int mat = b >> 2, tl = b & 3, tr = tl >> 1, tc = tl & 1;
        const float* W = (mat == 0) ? Wq : (mat == 1) ? Wk : (mat == 2) ? Wv : (mat == 3) ? Wo : Wg;
        // mat 0: 1/sqrt(32) * log2(e)  (exp2 path downstream)
        const float s = (mat == 0) ? 0.2550680544705824f : 1.f;
        const int rlo = t >> 6, col = t & 63;
        #pragma unroll
        for (int m = 0; m < 16; ++m) {
            int row = m * 4 + rlo;
            tile[row][col] = W[(size_t)(tr * 64 + row) * C_ + tc * 64 + col];
        }
        __syncthreads();
        #pragma unroll
        for (int m = 0; m < 16; ++m) {
            int n = tc * 64 + m * 4 + rlo;
            int c = tr * 64 + col;
            Wt[mat * 16384 + n * C_ + c] = f2b(tile[col][m * 4 + rlo] * s);
        }
    } else {
        #pragma unroll
        for (int m = 0; m < 2; ++m) {
            int idx = m * 256 + t;
            int h = idx >> 7, c = idx & 127;
            WbT[h * C_ + c] = Wbias[c * H_ + h] * 1.4426950408889634f;
        }
    }
}

// ---- Phase 1: LayerNorm + QKV + bias projection (vb 0..1023, 64 rows) ----
__device__ __forceinline__ void lnmm_body(
    int vb, int t, char* shraw,
    const float* __restrict__ pair, const float* __restrict__ ln_g, const float* __restrict__ ln_b,
    const u16* __restrict__ Wt, const float* __restrict__ WbT,
    u16* __restrict__ qh, u16* __restrict__ kh, u16* __restrict__ vh,
    float* __restrict__ biasN)
{
    auto zsh = reinterpret_cast<u16(*)[136]>(shraw);   // [64][136] = 17408 B

    const int p0 = vb * 64;
    const int row = t >> 2, seg = t & 3;

    float4 xv[8];
    float sum = 0.f, ss = 0.f;
    #pragma unroll
    for (int i = 0; i < 8; ++i) {
        int c = (seg + 4 * i) * 4;
        float4 x = *(const float4*)(pair + (size_t)(p0 + row) * C_ + c);
        xv[i] = x;
        sum += x.x + x.y + x.z + x.w;
        ss  += x.x * x.x + x.y * x.y + x.z * x.z + x.w * x.w;
    }
    sum += __shfl_xor(sum, 1); sum += __shfl_xor(sum, 2);
    ss  += __shfl_xor(ss, 1);  ss  += __shfl_xor(ss, 2);
    float mu  = sum * (1.0f / C_);
    float var = ss * (1.0f / C_) - mu * mu;
    float rs  = rsqrtf(fmaxf(var, 0.f) + 1e-5f);

    #pragma unroll
    for (int i = 0; i < 8; ++i) {
        int c = (seg + 4 * i) * 4;
        float4 g4 = *(const float4*)(ln_g + c);
        float4 b4 = *(const float4*)(ln_b + c);
        float4 x  = xv[i];
        float z0 = (x.x - mu) * rs * g4.x + b4.x;
        float z1 = (x.y - mu) * rs * g4.y + b4.y;
        float z2 = (x.z - mu) * rs * g4.z + b4.z;
        float z3 = (x.w - mu) * rs * g4.w + b4.w;
        *(u32*)&zsh[row][c]     = pk2(z0, z1);
        *(u32*)&zsh[row][c + 2] = pk2(z2, z3);
    }
    __syncthreads();

    const int w    = t >> 6;
    const int l15  = t & 15;
    const int quad = (t >> 4) & 3;

    bf16x8 zf[4][4];
    #pragma unroll
    for (int jt = 0; jt < 4; ++jt)
        #pragma unroll
        for (int kc = 0; kc < 4; ++kc)
            zf[jt][kc] = *(const bf16x8*)&zsh[jt * 16 + l15][kc * 32 + quad * 8];

    #pragma unroll
    for (int k = 0; k < 6; ++k) {
        const int tt = w * 6 + k;
        const int mat = tt >> 3, mt = tt & 7;
        f32x4 acc0 = {0.f,0.f,0.f,0.f}, acc1 = acc0, acc2 = acc0, acc3 = acc0;
        #pragma unroll
        for (int kc = 0; kc < 4; ++kc) {
            bf16x8 af = *(const bf16x8*)(Wt + (size_t)tt * 2048 + (size_t)l15 * 128 + kc * 32 + quad * 8);
            acc0 = __builtin_amdgcn_mfma_f32_16x16x32_bf16(af, zf[0][kc], acc0, 0, 0, 0);
            acc1 = __builtin_amdgcn_mfma_f32_16x16x32_bf16(af, zf[1][kc], acc1, 0, 0, 0);
            acc2 = __builtin_amdgcn_mfma_f32_16x16x32_bf16(af, zf[2][kc], acc2, 0, 0, 0);
            acc3 = __builtin_amdgcn_mfma_f32_16x16x32_bf16(af, zf[3][kc], acc3, 0, 0, 0);
        }
        u16* dst = (mat == 0) ? qh : (mat == 1) ? kh : vh;
        const int hh = mt >> 1;
        const int cb = (mt & 1) * 16 + quad * 4;
        f32x4 accs[4] = {acc0, acc1, acc2, acc3};
        #pragma unroll
        for (int jt = 0; jt < 4; ++jt) {
            const int p = p0 + jt * 16 + l15;
            *(uint2*)(dst + ((size_t)hh * NP_ + p) * D_ + cb) =
                make_uint2(pk2(accs[jt][0], accs[jt][1]), pk2(accs[jt][2], accs[jt][3]));
        }
    }

    // bias projection: thread (row, h=seg); biasN[h][p] fp32 natural
    {
        float a = 0.f;
        #pragma unroll
        for (int c8 = 0; c8 < C_; c8 += 8) {
            uint4 zz = *(const uint4*)&zsh[row][c8];
            float4 wb0 = *(const float4*)(WbT + seg * C_ + c8);
            float4 wb1 = *(const float4*)(WbT + seg * C_ + c8 + 4);
            a += bflo(zz.x) * wb0.x + bfhi(zz.x) * wb0.y
               + bflo(zz.y) * wb0.z + bfhi(zz.y) * wb0.w
               + bflo(zz.z) * wb1.x + bfhi(zz.z) * wb1.y
               + bflo(zz.w) * wb1.z + bfhi(zz.w) * wb1.w;
        }
        const int p = p0 + row;
        biasN[(size_t)seg * NP_ + p] = a;
    }
}

// ---- Phase 2: attention (vb 0..1023 = (i,h)) ----
__device__ __forceinline__ void attn_body(
    int vb, int t, char* shraw,
    u16* __restrict__ qh, const u16* __restrict__ kh, const u16* __restrict__ vh,
    const float* __restrict__ biasN)
{
    u16* Vsh = reinterpret_cast<u16*>(shraw);                       // D_*264*2 = 16896 B
    auto Psh = reinterpret_cast<u16(*)[16][40]>(shraw + 16896);     // 4*16*40*2 = 5120 B

    const int i = vb >> 2;
    const int h = vb & 3;
    const int w    = t >> 6;
    const int l15  = t & 15;
    const int quad = (t >> 4) & 3;
    const int jbase = w * 64;

    const u16* Kg = kh + ((size_t)h * NP_ + i * L_) * D_;
    const u16* Vg = vh + ((size_t)h * NP_ + i * L_) * D_;
    u16*       Qg = qh + ((size_t)h * NP_ + i * L_) * D_;

    #pragma unroll
    for (int jj = 0; jj < 4; ++jj) {
        int idx = t + jj * 256;
        int r = idx >> 2, sg = idx & 3;
        union { uint4 q; u16 s[8]; } u;
        u.q = *(const uint4*)(Vg + r * D_ + sg * 8);
        #pragma unroll
        for (int m = 0; m < 8; ++m) Vsh[(sg * 8 + m) * 264 + r] = u.s[m];
    }

    bf16x8 qf[4];
    #pragma unroll
    for (int jt = 0; jt < 4; ++jt)
        qf[jt] = *(const bf16x8*)(Qg + (size_t)(jbase + jt * 16 + l15) * D_ + quad * 8);

    __syncthreads();

    const f32x4 z4 = {0.f, 0.f, 0.f, 0.f};
    f32x4 oacc[4][2], osum[4];
    #pragma unroll
    for (int jt = 0; jt < 4; ++jt) {
        oacc[jt][0] = z4; oacc[jt][1] = z4; osum[jt] = z4;
    }

    bf16x8 onesb;
    { union { u32 u[4]; bf16x8 v; } ob;
      ob.u[0] = ob.u[1] = ob.u[2] = ob.u[3] = 0x3F803F80u; onesb = ob.v; }

    const float* bN = biasN + (size_t)h * NP_;

    bf16x8 kb0 = *(const bf16x8*)(Kg + (size_t)l15 * D_ + quad * 8);
    bf16x8 kb1 = *(const bf16x8*)(Kg + (size_t)(16 + l15) * D_ + quad * 8);

    for (int kc = 0; kc < 8; ++kc) {
        bf16x8 nb0, nb1;
        if (kc < 7) {
            nb0 = *(const bf16x8*)(Kg + (size_t)((kc + 1) * 32 + l15) * D_ + quad * 8);
            nb1 = *(const bf16x8*)(Kg + (size_t)((kc + 1) * 32 + 16 + l15) * D_ + quad * 8);
        }
        bf16x8 vb0 = *(const bf16x8*)&Vsh[l15 * 264 + kc * 32 + quad * 8];
        bf16x8 vb1 = *(const bf16x8*)&Vsh[(16 + l15) * 264 + kc * 32 + quad * 8];

        #pragma unroll
        for (int jt = 0; jt < 4; ++jt) {
            f32x4 s0 = __builtin_amdgcn_mfma_f32_16x16x32_bf16(kb0, qf[jt], z4, 0, 0, 0);
            f32x4 s1 = __builtin_amdgcn_mfma_f32_16x16x32_bf16(kb1, qf[jt], z4, 0, 0, 0);

            const float* bp = bN + (size_t)(jbase + jt * 16 + l15) * L_ + kc * 32 + quad * 4;
            float4 bv0 = *(const float4*)bp;
            float4 bv1 = *(const float4*)(bp + 16);

            float e0[4], e1[4];
            e0[0] = __builtin_amdgcn_exp2f(s0[0] + bv0.x);
            e0[1] = __builtin_amdgcn_exp2f(s0[1] + bv0.y);
            e0[2] = __builtin_amdgcn_exp2f(s0[2] + bv0.z);
            e0[3] = __builtin_amdgcn_exp2f(s0[3] + bv0.w);
            e1[0] = __builtin_amdgcn_exp2f(s1[0] + bv1.x);
            e1[1] = __builtin_amdgcn_exp2f(s1[1] + bv1.y);
            e1[2] = __builtin_amdgcn_exp2f(s1[2] + bv1.z);
            e1[3] = __builtin_amdgcn_exp2f(s1[3] + bv1.w);

            u32 w0, w1, w2, w3;
            asm("v_cvt_pk_bf16_f32 %0, %1, %2" : "=v"(w0) : "v"(e0[0]), "v"(e0[1]));
            asm("v_cvt_pk_bf16_f32 %0, %1, %2" : "=v"(w1) : "v"(e0[2]), "v"(e0[3]));
            asm("v_cvt_pk_bf16_f32 %0, %1, %2" : "=v"(w2) : "v"(e1[0]), "v"(e1[1]));
            asm("v_cvt_pk_bf16_f32 %0, %1, %2" : "=v"(w3) : "v"(e1[2]), "v"(e1[3]));
            *(uint2*)&Psh[w][l15][quad * 4]      = make_uint2(w0, w1);
            *(uint2*)&Psh[w][l15][16 + quad * 4] = make_uint2(w2, w3);

            bf16x8 pa = *(const bf16x8*)&Psh[w][l15][quad * 8];
            oacc[jt][0] = __builtin_amdgcn_mfma_f32_16x16x32_bf16(pa, vb0,   oacc[jt][0], 0, 0, 0);
            oacc[jt][1] = __builtin_amdgcn_mfma_f32_16x16x32_bf16(pa, vb1,   oacc[jt][1], 0, 0, 0);
            osum[jt]    = __builtin_amdgcn_mfma_f32_16x16x32_bf16(pa, onesb, osum[jt],    0, 0, 0);
        }
        kb0 = nb0; kb1 = nb1;
    }

    #pragma unroll
    for (int jt = 0; jt < 4; ++jt) {
        #pragma unroll
        for (int r = 0; r < 4; ++r) {
            float rn = 1.f / osum[jt][r];
            size_t rowo = (size_t)(jbase + jt * 16 + quad * 4 + r) * D_;
            Qg[rowo + l15]      = f2b(oacc[jt][0][r] * rn);
            Qg[rowo + 16 + l15] = f2b(oacc[jt][1][r] * rn);
        }
    }
}

// ---- Phase 3: output projection + gate (vb 0..511, 128 rows) ----
__device__ __forceinline__ void out_body(
    int vb, int t,
    const u16* __restrict__ aoh, const float* __restrict__ pair,
    const u16* __restrict__ Wt, const float* __restrict__ bo,
    const float* __restrict__ bg, float* __restrict__ out)
{
    const int p0 = vb * 128;
    const int w    = t >> 6;
    const int l15  = t & 15;
    const int quad = (t >> 4) & 3;

    bf16x8 aof[2][4], pf[2][4];
    int prow[2];
    #pragma unroll
    for (int g = 0; g < 2; ++g) {
        prow[g] = p0 + w * 32 + g * 16 + l15;
        #pragma unroll
        for (int kc = 0; kc < 4; ++kc) {
            aof[g][kc] = *(const bf16x8*)(aoh + ((size_t)kc * NP_ + prow[g]) * D_ + quad * 8);
            const float* pp = pair + (size_t)prow[g] * C_ + kc * 32 + quad * 8;
            pf[g][kc] = pack8(*(const float4*)pp, *(const float4*)(pp + 4));
        }
    }

    const u16* WoT = Wt + 3 * 16384;
    const u16* WgT = Wt + 4 * 16384;

    #pragma unroll
    for (int nt = 0; nt < 8; ++nt) {
        f32x4 accO0 = {0.f,0.f,0.f,0.f}, accO1 = accO0, accG0 = accO0, accG1 = accO0;
        #pragma unroll
        for (int kc = 0; kc < 4; ++kc) {
            bf16x8 awo = *(const bf16x8*)(WoT + (size_t)(nt * 16 + l15) * 128 + kc * 32 + quad * 8);
            bf16x8 awg = *(const bf16x8*)(WgT + (size_t)(nt * 16 + l15) * 128 + kc * 32 + quad * 8);
            accO0 = __builtin_amdgcn_mfma_f32_16x16x32_bf16(awo, aof[0][kc], accO0, 0, 0, 0);
            accO1 = __builtin_amdgcn_mfma_f32_16x16x32_bf16(awo, aof[1][kc], accO1, 0, 0, 0);
            accG0 = __builtin_amdgcn_mfma_f32_16x16x32_bf16(awg, pf[0][kc],  accG0, 0, 0, 0);
            accG1 = __builtin_amdgcn_mfma_f32_16x16x32_bf16(awg, pf[1][kc],  accG1, 0, 0, 0);
        }
        const int ch = nt * 16 + quad * 4;
        float4 bo4 = *(const float4*)(bo + ch);
        float4 bg4 = *(const float4*)(bg + ch);
        f32x4 aO[2] = {accO0, accO1}, aG[2] = {accG0, accG1};
        #pragma unroll
        for (int g = 0; g < 2; ++g) {
            float4 pr = *(const float4*)(pair + (size_t)prow[g] * C_ + ch);
            float4 r;
            r.x = pr.x + (1.f / (1.f + __expf(-(aG[g][0] + bg4.x)))) * (aO[g][0] + bo4.x);
            r.y = pr.y + (1.f / (1.f + __expf(-(aG[g][1] + bg4.y)))) * (aO[g][1] + bo4.y);
            r.z = pr.z + (1.f / (1.f + __expf(-(aG[g][2] + bg4.z)))) * (aO[g][2] + bo4.z);
            r.w = pr.w + (1.f / (1.f + __expf(-(aG[g][3] + bg4.w)))) * (aO[g][3] + bo4.w);
            *(float4*)(out + (size_t)prow[g] * C_ + ch) = r;
        }
    }
}

// ===========================================================================
// Fused cooperative kernel: grid = 1024 x 256, 4 blocks/CU (LDS 22016 -> 7
// LDS-wise; launch_bounds(256,4) caps VGPR at 128 -> 4 waves/SIMD -> the
// cooperative occupancy check passes). 3 grid.sync()s replace 3 inter-kernel
// gaps (>=45 us of the 204 us total was outside all kernels).
// ===========================================================================
__global__ __launch_bounds__(256, 4) void k_fused(
    const float* __restrict__ pair, const float* __restrict__ ln_g, const float* __restrict__ ln_b,
    const float* __restrict__ Wq, const float* __restrict__ Wk, const float* __restrict__ Wv,
    const float* __restrict__ Wbias, const float* __restrict__ Wo, const float* __restrict__ bo,
    const float* __restrict__ Wg, const float* __restrict__ bg, float* __restrict__ out,
    u16* __restrict__ Wt, float* __restrict__ WbT,
    u16* __restrict__ qh, u16* __restrict__ kh, u16* __restrict__ vh, float* __restrict__ biasN)
{
    __shared__ __align__(16) char shraw[22016];
    cg::grid_group grid = cg::this_grid();
    const int t = threadIdx.x;

    // Phase 0: prep
    for (int vb = blockIdx.x; vb < 21; vb += gridDim.x)
        prep_body(vb, t, shraw, Wq, Wk, Wv, Wo, Wg, Wbias, Wt, WbT);
    __threadfence();
    grid.sync();

    // Phase 1: LN + QKV + bias
    for (int vb = blockIdx.x; vb < 1024; vb += gridDim.x)
        lnmm_body(vb, t, shraw, pair, ln_g, ln_b, Wt, WbT, qh, kh, vh, biasN);
    __threadfence();
    grid.sync();

    // Phase 2: attention (O written in place of Q)
    for (int vb = blockIdx.x; vb < 1024; vb += gridDim.x)
        attn_body(vb, t, shraw, qh, kh, vh, biasN);
    __threadfence();
    grid.sync();

    // Phase 3: out projection + gate
    for (int vb = blockIdx.x; vb < 512; vb += gridDim.x)
        out_body(vb, t, qh, pair, Wt, bo, bg, out);
}

// ===========================================================================
// Fallback standalone kernels (round-3 exact), used if cooperative launch
// is rejected (e.g., unsupported under graph capture).
// ===========================================================================
__global__ __launch_bounds__(256) void k_prep(
    const float* __restrict__ Wq, const float* __restrict__ Wk, const float* __restrict__ Wv,
    const float* __restrict__ Wo, const float* __restrict__ Wg,
    const float* __restrict__ Wbias, u16* __restrict__ Wt, float* __restrict__ WbT)
{
    __shared__ __align__(16) char shraw[16640];
    prep_body(blockIdx.x, threadIdx.x, shraw, Wq, Wk, Wv, Wo, Wg, Wbias, Wt, WbT);
}

__global__ __launch_bounds__(256) void k_lnmm(
    const float* __restrict__ pair, const float* __restrict__ ln_g, const float* __restrict__ ln_b,
    const u16* __restrict__ Wt, const float* __restrict__ WbT,
    u16* __restrict__ qh, u16* __restrict__ kh, u16* __restrict__ vh,
    float* __restrict__ biasN)
{
    __shared__ __align__(16) char shraw[17408];
    lnmm_body(blockIdx.x, threadIdx.x, shraw, pair, ln_g, ln_b, Wt, WbT, qh, kh, vh, biasN);
}

__global__ __launch_bounds__(256, 4) void k_attn(
    u16* __restrict__ qh, const u16* __restrict__ kh, const u16* __restrict__ vh,
    const float* __restrict__ biasN)
{
    __shared__ __align__(16) char shraw[22016];
    attn_body(blockIdx.x, threadIdx.x, shraw, qh, kh, vh, biasN);
}

__global__ __launch_bounds__(256) void k_out(
    const u16* __restrict__ aoh, const float* __restrict__ pair,
    const u16* __restrict__ Wt, const float* __restrict__ bo,
    const float* __restrict__ bg, float* __restrict__ out)
{
    out_body(blockIdx.x, threadIdx.x, aoh, pair, Wt, bo, bg, out);
}

// ---------------------------------------------------------------------------
// Workspace (~51.5 MB):
//   [0, 1.0 MB)    biasN fp32 [H][j][k]   (natural layout, LOG2E-scaled)
//   [+,  +16.8MB)  qh bf16 [H][NP][32]    (Q in, O out in place)
//   [+,  +16.8MB)  kh
//   [+,  +16.8MB)  vh
//   [+,  +160K)    Wt bf16 [5][128][128]
//   [+,  +2K)      WbT fp32 [4][128]
// ---------------------------------------------------------------------------
extern "C" void kernel_launch(void* const* d_in, const int* in_sizes, int n_in,
                              void* d_out, int out_size, void* d_ws, size_t ws_size,
                              hipStream_t stream) {
    const float* pair  = (const float*)d_in[0];
    const float* ln_g  = (const float*)d_in[1];
    const float* ln_b  = (const float*)d_in[2];
    const float* Wq    = (const float*)d_in[3];
    const float* Wk    = (const float*)d_in[4];
    const float* Wv    = (const float*)d_in[5];
    const float* Wbias = (const float*)d_in[6];
    const float* Wo    = (const float*)d_in[7];
    const float* bo    = (const float*)d_in[8];
    const float* Wg    = (const float*)d_in[9];
    const float* bg    = (const float*)d_in[10];
    float* out = (float*)d_out;

    float* biasN = (float*)d_ws;                      // 1.0 MB fp32
    u16* qh = (u16*)(biasN + (size_t)H_ * NP_);
    u16* kh = qh + (size_t)NP_ * C_;
    u16* vh = kh + (size_t)NP_ * C_;
    u16* Wt = vh + (size_t)NP_ * C_;
    float* WbT = (float*)(Wt + 5 * 16384);

    void* kargs[] = {
        (void*)&pair, (void*)&ln_g, (void*)&ln_b,
        (void*)&Wq, (void*)&Wk, (void*)&Wv,
        (void*)&Wbias, (void*)&Wo, (void*)&bo,
        (void*)&Wg, (void*)&bg, (void*)&out,
        (void*)&Wt, (void*)&WbT,
        (void*)&qh, (void*)&kh, (void*)&vh, (void*)&biasN
    };
    hipError_t e = hipLaunchCooperativeKernel((void*)k_fused, dim3(1024), dim3(256),
                                              kargs, 0, stream);
    if (e != hipSuccess) {
        // Fallback: round-3 four-dispatch pipeline.
        k_prep<<<21, 256, 0, stream>>>(Wq, Wk, Wv, Wo, Wg, Wbias, Wt, WbT);
        k_lnmm<<<NP_ / 64, 256, 0, stream>>>(pair, ln_g, ln_b, Wt, WbT, qh, kh, vh, biasN);
        k_attn<<<L_ * H_, 256, 0, stream>>>(qh, kh, vh, biasN);
        k_out<<<NP_ / 128, 256, 0, stream>>>(qh, pair, Wt, bo, bg, out);
    }
}

// Round 6
// 202.301 us; speedup vs baseline: 5.1493x; 5.1493x over previous
//
#include <hip/hip_runtime.h>
#include <hip/hip_cooperative_groups.h>
#include <cstdint>
#include <cstddef>

namespace cg = cooperative_groups;

#define L_ 256
#define C_ 128
#define H_ 4
#define D_ 32
#define NP_ (L_ * L_)

typedef unsigned short u16;
typedef uint32_t u32;
typedef __attribute__((ext_vector_type(8))) short bf16x8;   // 4 VGPRs: MFMA A/B frag
typedef __attribute__((ext_vector_type(4))) float f32x4;    // MFMA C/D frag

__device__ __forceinline__ float bflo(u32 u) { union { u32 i; float f; } v; v.i = u << 16; return v.f; }
__device__ __forceinline__ float bfhi(u32 u) { union { u32 i; float f; } v; v.i = u & 0xffff0000u; return v.f; }
__device__ __forceinline__ u16 f2b(float f) {
    u32 x = __float_as_uint(f);
    return (u16)((x + 0x7fffu + ((x >> 16) & 1u)) >> 16);
}
__device__ __forceinline__ u32 pk2(float lo, float hi) {
    return ((u32)f2b(hi) << 16) | (u32)f2b(lo);
}
__device__ __forceinline__ bf16x8 pack8(float4 a, float4 b) {
    union { u32 u[4]; bf16x8 v; } r;
    r.u[0] = pk2(a.x, a.y); r.u[1] = pk2(a.z, a.w);
    r.u[2] = pk2(b.x, b.y); r.u[3] = pk2(b.z, b.w);
    return r.v;
}

// ===========================================================================
// Phase bodies (round-3 verbatim, parameterized by virtual block id).
// Round-5 lesson: the fused kernel is correct but launch_bounds(256,4) only
// sets MIN waves/EU -> allocator chased 8 waves/EU, alloc'd 64 VGPR, spilled
// (738 MB HBM, 998 us). This round pins waves_per_eu(4,4) (max too) so the
// allocator keeps the full 128-VGPR budget, and a hipFuncGetAttributes spill
// guard falls back to the round-3 pipeline (204 us) if codegen misbehaves.
// ===========================================================================

// ---- Phase 0: weight prep (vb 0..20) ----
__device__ __forceinline__ void prep_body(
    int b, int t, char* shraw,
    const float* __restrict__ Wq, const float* __restrict__ Wk, const float* __restrict__ Wv,
    const float* __restrict__ Wo, const float* __restrict__ Wg,
    const float* __restrict__ Wbias, u16* __restrict__ Wt, float* __restrict__ WbT)
{
    auto tile = reinterpret_cast<float(*)[65]>(shraw);   // [64][65] = 16640 B
    if (b < 20) {
        const int mat = b >> 2, tl = b & 3, tr = tl >> 1, tc = tl & 1;
        const float* W = (mat == 0) ? Wq : (mat == 1) ? Wk : (mat == 2) ? Wv : (mat == 3) ? Wo : Wg;
        // mat 0: 1/sqrt(32) * log2(e)  (exp2 path downstream)
        const float s = (mat == 0) ? 0.2550680544705824f : 1.f;
        const int rlo = t >> 6, col = t & 63;
        #pragma unroll
        for (int m = 0; m < 16; ++m) {
            int row = m * 4 + rlo;
            tile[row][col] = W[(size_t)(tr * 64 + row) * C_ + tc * 64 + col];
        }
        __syncthreads();
        #pragma unroll
        for (int m = 0; m < 16; ++m) {
            int n = tc * 64 + m * 4 + rlo;
            int c = tr * 64 + col;
            Wt[mat * 16384 + n * C_ + c] = f2b(tile[col][m * 4 + rlo] * s);
        }
    } else {
        #pragma unroll
        for (int m = 0; m < 2; ++m) {
            int idx = m * 256 + t;
            int h = idx >> 7, c = idx & 127;
            WbT[h * C_ + c] = Wbias[c * H_ + h] * 1.4426950408889634f;
        }
    }
}

// ---- Phase 1: LayerNorm + QKV + bias projection (vb 0..1023, 64 rows) ----
__device__ __forceinline__ void lnmm_body(
    int vb, int t, char* shraw,
    const float* __restrict__ pair, const float* __restrict__ ln_g, const float* __restrict__ ln_b,
    const u16* __restrict__ Wt, const float* __restrict__ WbT,
    u16* __restrict__ qh, u16* __restrict__ kh, u16* __restrict__ vh,
    float* __restrict__ biasN)
{
    auto zsh = reinterpret_cast<u16(*)[136]>(shraw);   // [64][136] = 17408 B

    const int p0 = vb * 64;
    const int row = t >> 2, seg = t & 3;

    float4 xv[8];
    float sum = 0.f, ss = 0.f;
    #pragma unroll
    for (int i = 0; i < 8; ++i) {
        int c = (seg + 4 * i) * 4;
        float4 x = *(const float4*)(pair + (size_t)(p0 + row) * C_ + c);
        xv[i] = x;
        sum += x.x + x.y + x.z + x.w;
        ss  += x.x * x.x + x.y * x.y + x.z * x.z + x.w * x.w;
    }
    sum += __shfl_xor(sum, 1); sum += __shfl_xor(sum, 2);
    ss  += __shfl_xor(ss, 1);  ss  += __shfl_xor(ss, 2);
    float mu  = sum * (1.0f / C_);
    float var = ss * (1.0f / C_) - mu * mu;
    float rs  = rsqrtf(fmaxf(var, 0.f) + 1e-5f);

    #pragma unroll
    for (int i = 0; i < 8; ++i) {
        int c = (seg + 4 * i) * 4;
        float4 g4 = *(const float4*)(ln_g + c);
        float4 b4 = *(const float4*)(ln_b + c);
        float4 x  = xv[i];
        float z0 = (x.x - mu) * rs * g4.x + b4.x;
        float z1 = (x.y - mu) * rs * g4.y + b4.y;
        float z2 = (x.z - mu) * rs * g4.z + b4.z;
        float z3 = (x.w - mu) * rs * g4.w + b4.w;
        *(u32*)&zsh[row][c]     = pk2(z0, z1);
        *(u32*)&zsh[row][c + 2] = pk2(z2, z3);
    }
    __syncthreads();

    const int w    = t >> 6;
    const int l15  = t & 15;
    const int quad = (t >> 4) & 3;

    bf16x8 zf[4][4];
    #pragma unroll
    for (int jt = 0; jt < 4; ++jt)
        #pragma unroll
        for (int kc = 0; kc < 4; ++kc)
            zf[jt][kc] = *(const bf16x8*)&zsh[jt * 16 + l15][kc * 32 + quad * 8];

    #pragma unroll
    for (int k = 0; k < 6; ++k) {
        const int tt = w * 6 + k;
        const int mat = tt >> 3, mt = tt & 7;
        f32x4 acc0 = {0.f,0.f,0.f,0.f}, acc1 = acc0, acc2 = acc0, acc3 = acc0;
        #pragma unroll
        for (int kc = 0; kc < 4; ++kc) {
            bf16x8 af = *(const bf16x8*)(Wt + (size_t)tt * 2048 + (size_t)l15 * 128 + kc * 32 + quad * 8);
            acc0 = __builtin_amdgcn_mfma_f32_16x16x32_bf16(af, zf[0][kc], acc0, 0, 0, 0);
            acc1 = __builtin_amdgcn_mfma_f32_16x16x32_bf16(af, zf[1][kc], acc1, 0, 0, 0);
            acc2 = __builtin_amdgcn_mfma_f32_16x16x32_bf16(af, zf[2][kc], acc2, 0, 0, 0);
            acc3 = __builtin_amdgcn_mfma_f32_16x16x32_bf16(af, zf[3][kc], acc3, 0, 0, 0);
        }
        u16* dst = (mat == 0) ? qh : (mat == 1) ? kh : vh;
        const int hh = mt >> 1;
        const int cb = (mt & 1) * 16 + quad * 4;
        f32x4 accs[4] = {acc0, acc1, acc2, acc3};
        #pragma unroll
        for (int jt = 0; jt < 4; ++jt) {
            const int p = p0 + jt * 16 + l15;
            *(uint2*)(dst + ((size_t)hh * NP_ + p) * D_ + cb) =
                make_uint2(pk2(accs[jt][0], accs[jt][1]), pk2(accs[jt][2], accs[jt][3]));
        }
    }

    // bias projection: thread (row, h=seg); biasN[h][p] fp32 natural
    {
        float a = 0.f;
        #pragma unroll
        for (int c8 = 0; c8 < C_; c8 += 8) {
            uint4 zz = *(const uint4*)&zsh[row][c8];
            float4 wb0 = *(const float4*)(WbT + seg * C_ + c8);
            float4 wb1 = *(const float4*)(WbT + seg * C_ + c8 + 4);
            a += bflo(zz.x) * wb0.x + bfhi(zz.x) * wb0.y
               + bflo(zz.y) * wb0.z + bfhi(zz.y) * wb0.w
               + bflo(zz.z) * wb1.x + bfhi(zz.z) * wb1.y
               + bflo(zz.w) * wb1.z + bfhi(zz.w) * wb1.w;
        }
        const int p = p0 + row;
        biasN[(size_t)seg * NP_ + p] = a;
    }
}

// ---- Phase 2: attention (vb 0..1023 = (i,h)) ----
__device__ __forceinline__ void attn_body(
    int vb, int t, char* shraw,
    u16* __restrict__ qh, const u16* __restrict__ kh, const u16* __restrict__ vh,
    const float* __restrict__ biasN)
{
    u16* Vsh = reinterpret_cast<u16*>(shraw);                       // D_*264*2 = 16896 B
    auto Psh = reinterpret_cast<u16(*)[16][40]>(shraw + 16896);     // 4*16*40*2 = 5120 B

    const int i = vb >> 2;
    const int h = vb & 3;
    const int w    = t >> 6;
    const int l15  = t & 15;
    const int quad = (t >> 4) & 3;
    const int jbase = w * 64;

    const u16* Kg = kh + ((size_t)h * NP_ + i * L_) * D_;
    const u16* Vg = vh + ((size_t)h * NP_ + i * L_) * D_;
    u16*       Qg = qh + ((size_t)h * NP_ + i * L_) * D_;

    #pragma unroll
    for (int jj = 0; jj < 4; ++jj) {
        int idx = t + jj * 256;
        int r = idx >> 2, sg = idx & 3;
        union { uint4 q; u16 s[8]; } u;
        u.q = *(const uint4*)(Vg + r * D_ + sg * 8);
        #pragma unroll
        for (int m = 0; m < 8; ++m) Vsh[(sg * 8 + m) * 264 + r] = u.s[m];
    }

    bf16x8 qf[4];
    #pragma unroll
    for (int jt = 0; jt < 4; ++jt)
        qf[jt] = *(const bf16x8*)(Qg + (size_t)(jbase + jt * 16 + l15) * D_ + quad * 8);

    __syncthreads();

    const f32x4 z4 = {0.f, 0.f, 0.f, 0.f};
    f32x4 oacc[4][2], osum[4];
    #pragma unroll
    for (int jt = 0; jt < 4; ++jt) {
        oacc[jt][0] = z4; oacc[jt][1] = z4; osum[jt] = z4;
    }

    bf16x8 onesb;
    { union { u32 u[4]; bf16x8 v; } ob;
      ob.u[0] = ob.u[1] = ob.u[2] = ob.u[3] = 0x3F803F80u; onesb = ob.v; }

    const float* bN = biasN + (size_t)h * NP_;

    bf16x8 kb0 = *(const bf16x8*)(Kg + (size_t)l15 * D_ + quad * 8);
    bf16x8 kb1 = *(const bf16x8*)(Kg + (size_t)(16 + l15) * D_ + quad * 8);

    for (int kc = 0; kc < 8; ++kc) {
        bf16x8 nb0, nb1;
        if (kc < 7) {
            nb0 = *(const bf16x8*)(Kg + (size_t)((kc + 1) * 32 + l15) * D_ + quad * 8);
            nb1 = *(const bf16x8*)(Kg + (size_t)((kc + 1) * 32 + 16 + l15) * D_ + quad * 8);
        }
        bf16x8 vb0 = *(const bf16x8*)&Vsh[l15 * 264 + kc * 32 + quad * 8];
        bf16x8 vb1 = *(const bf16x8*)&Vsh[(16 + l15) * 264 + kc * 32 + quad * 8];

        #pragma unroll
        for (int jt = 0; jt < 4; ++jt) {
            f32x4 s0 = __builtin_amdgcn_mfma_f32_16x16x32_bf16(kb0, qf[jt], z4, 0, 0, 0);
            f32x4 s1 = __builtin_amdgcn_mfma_f32_16x16x32_bf16(kb1, qf[jt], z4, 0, 0, 0);

            const float* bp = bN + (size_t)(jbase + jt * 16 + l15) * L_ + kc * 32 + quad * 4;
            float4 bv0 = *(const float4*)bp;
            float4 bv1 = *(const float4*)(bp + 16);

            float e0[4], e1[4];
            e0[0] = __builtin_amdgcn_exp2f(s0[0] + bv0.x);
            e0[1] = __builtin_amdgcn_exp2f(s0[1] + bv0.y);
            e0[2] = __builtin_amdgcn_exp2f(s0[2] + bv0.z);
            e0[3] = __builtin_amdgcn_exp2f(s0[3] + bv0.w);
            e1[0] = __builtin_amdgcn_exp2f(s1[0] + bv1.x);
            e1[1] = __builtin_amdgcn_exp2f(s1[1] + bv1.y);
            e1[2] = __builtin_amdgcn_exp2f(s1[2] + bv1.z);
            e1[3] = __builtin_amdgcn_exp2f(s1[3] + bv1.w);

            u32 w0, w1, w2, w3;
            asm("v_cvt_pk_bf16_f32 %0, %1, %2" : "=v"(w0) : "v"(e0[0]), "v"(e0[1]));
            asm("v_cvt_pk_bf16_f32 %0, %1, %2" : "=v"(w1) : "v"(e0[2]), "v"(e0[3]));
            asm("v_cvt_pk_bf16_f32 %0, %1, %2" : "=v"(w2) : "v"(e1[0]), "v"(e1[1]));
            asm("v_cvt_pk_bf16_f32 %0, %1, %2" : "=v"(w3) : "v"(e1[2]), "v"(e1[3]));
            *(uint2*)&Psh[w][l15][quad * 4]      = make_uint2(w0, w1);
            *(uint2*)&Psh[w][l15][16 + quad * 4] = make_uint2(w2, w3);

            bf16x8 pa = *(const bf16x8*)&Psh[w][l15][quad * 8];
            oacc[jt][0] = __builtin_amdgcn_mfma_f32_16x16x32_bf16(pa, vb0,   oacc[jt][0], 0, 0, 0);
            oacc[jt][1] = __builtin_amdgcn_mfma_f32_16x16x32_bf16(pa, vb1,   oacc[jt][1], 0, 0, 0);
            osum[jt]    = __builtin_amdgcn_mfma_f32_16x16x32_bf16(pa, onesb, osum[jt],    0, 0, 0);
        }
        kb0 = nb0; kb1 = nb1;
    }

    #pragma unroll
    for (int jt = 0; jt < 4; ++jt) {
        #pragma unroll
        for (int r = 0; r < 4; ++r) {
            float rn = 1.f / osum[jt][r];
            size_t rowo = (size_t)(jbase + jt * 16 + quad * 4 + r) * D_;
            Qg[rowo + l15]      = f2b(oacc[jt][0][r] * rn);
            Qg[rowo + 16 + l15] = f2b(oacc[jt][1][r] * rn);
        }
    }
}

// ---- Phase 3: output projection + gate (vb 0..511, 128 rows) ----
__device__ __forceinline__ void out_body(
    int vb, int t,
    const u16* __restrict__ aoh, const float* __restrict__ pair,
    const u16* __restrict__ Wt, const float* __restrict__ bo,
    const float* __restrict__ bg, float* __restrict__ out)
{
    const int p0 = vb * 128;
    const int w    = t >> 6;
    const int l15  = t & 15;
    const int quad = (t >> 4) & 3;

    bf16x8 aof[2][4], pf[2][4];
    int prow[2];
    #pragma unroll
    for (int g = 0; g < 2; ++g) {
        prow[g] = p0 + w * 32 + g * 16 + l15;
        #pragma unroll
        for (int kc = 0; kc < 4; ++kc) {
            aof[g][kc] = *(const bf16x8*)(aoh + ((size_t)kc * NP_ + prow[g]) * D_ + quad * 8);
            const float* pp = pair + (size_t)prow[g] * C_ + kc * 32 + quad * 8;
            pf[g][kc] = pack8(*(const float4*)pp, *(const float4*)(pp + 4));
        }
    }

    const u16* WoT = Wt + 3 * 16384;
    const u16* WgT = Wt + 4 * 16384;

    #pragma unroll
    for (int nt = 0; nt < 8; ++nt) {
        f32x4 accO0 = {0.f,0.f,0.f,0.f}, accO1 = accO0, accG0 = accO0, accG1 = accO0;
        #pragma unroll
        for (int kc = 0; kc < 4; ++kc) {
            bf16x8 awo = *(const bf16x8*)(WoT + (size_t)(nt * 16 + l15) * 128 + kc * 32 + quad * 8);
            bf16x8 awg = *(const bf16x8*)(WgT + (size_t)(nt * 16 + l15) * 128 + kc * 32 + quad * 8);
            accO0 = __builtin_amdgcn_mfma_f32_16x16x32_bf16(awo, aof[0][kc], accO0, 0, 0, 0);
            accO1 = __builtin_amdgcn_mfma_f32_16x16x32_bf16(awo, aof[1][kc], accO1, 0, 0, 0);
            accG0 = __builtin_amdgcn_mfma_f32_16x16x32_bf16(awg, pf[0][kc],  accG0, 0, 0, 0);
            accG1 = __builtin_amdgcn_mfma_f32_16x16x32_bf16(awg, pf[1][kc],  accG1, 0, 0, 0);
        }
        const int ch = nt * 16 + quad * 4;
        float4 bo4 = *(const float4*)(bo + ch);
        float4 bg4 = *(const float4*)(bg + ch);
        f32x4 aO[2] = {accO0, accO1}, aG[2] = {accG0, accG1};
        #pragma unroll
        for (int g = 0; g < 2; ++g) {
            float4 pr = *(const float4*)(pair + (size_t)prow[g] * C_ + ch);
            float4 r;
            r.x = pr.x + (1.f / (1.f + __expf(-(aG[g][0] + bg4.x)))) * (aO[g][0] + bo4.x);
            r.y = pr.y + (1.f / (1.f + __expf(-(aG[g][1] + bg4.y)))) * (aO[g][1] + bo4.y);
            r.z = pr.z + (1.f / (1.f + __expf(-(aG[g][2] + bg4.z)))) * (aO[g][2] + bo4.z);
            r.w = pr.w + (1.f / (1.f + __expf(-(aG[g][3] + bg4.w)))) * (aO[g][3] + bo4.w);
            *(float4*)(out + (size_t)prow[g] * C_ + ch) = r;
        }
    }
}

// ===========================================================================
// Fused cooperative kernel. waves_per_eu(4,4) pins BOTH min and max waves/EU
// at 4 -> the allocator keeps the full 512/4 = 128 VGPR budget and has no
// incentive to squeeze to 64-with-spills (round-5 failure mode). Grid 1024 =
// 4 blocks/CU. 3 grid.sync()s replace 3 inter-kernel gaps.
// ===========================================================================
__global__ __launch_bounds__(256)
__attribute__((amdgpu_waves_per_eu(4, 4)))
void k_fused(
    const float* __restrict__ pair, const float* __restrict__ ln_g, const float* __restrict__ ln_b,
    const float* __restrict__ Wq, const float* __restrict__ Wk, const float* __restrict__ Wv,
    const float* __restrict__ Wbias, const float* __restrict__ Wo, const float* __restrict__ bo,
    const float* __restrict__ Wg, const float* __restrict__ bg, float* __restrict__ out,
    u16* __restrict__ Wt, float* __restrict__ WbT,
    u16* __restrict__ qh, u16* __restrict__ kh, u16* __restrict__ vh, float* __restrict__ biasN)
{
    __shared__ __align__(16) char shraw[22016];
    cg::grid_group grid = cg::this_grid();
    const int t = threadIdx.x;

    // Phase 0: prep
    for (int vb = blockIdx.x; vb < 21; vb += gridDim.x)
        prep_body(vb, t, shraw, Wq, Wk, Wv, Wo, Wg, Wbias, Wt, WbT);
    __threadfence();
    grid.sync();

    // Phase 1: LN + QKV + bias
    for (int vb = blockIdx.x; vb < 1024; vb += gridDim.x)
        lnmm_body(vb, t, shraw, pair, ln_g, ln_b, Wt, WbT, qh, kh, vh, biasN);
    __threadfence();
    grid.sync();

    // Phase 2: attention (O written in place of Q)
    for (int vb = blockIdx.x; vb < 1024; vb += gridDim.x)
        attn_body(vb, t, shraw, qh, kh, vh, biasN);
    __threadfence();
    grid.sync();

    // Phase 3: out projection + gate
    for (int vb = blockIdx.x; vb < 512; vb += gridDim.x)
        out_body(vb, t, qh, pair, Wt, bo, bg, out);
}

// ===========================================================================
// Fallback standalone kernels (round-3 exact, 204 us total), used if the
// fused kernel spills (hipFuncGetAttributes guard) or the cooperative
// launch is rejected.
// ===========================================================================
__global__ __launch_bounds__(256) void k_prep(
    const float* __restrict__ Wq, const float* __restrict__ Wk, const float* __restrict__ Wv,
    const float* __restrict__ Wo, const float* __restrict__ Wg,
    const float* __restrict__ Wbias, u16* __restrict__ Wt, float* __restrict__ WbT)
{
    __shared__ __align__(16) char shraw[16640];
    prep_body(blockIdx.x, threadIdx.x, shraw, Wq, Wk, Wv, Wo, Wg, Wbias, Wt, WbT);
}

__global__ __launch_bounds__(256) void k_lnmm(
    const float* __restrict__ pair, const float* __restrict__ ln_g, const float* __restrict__ ln_b,
    const u16* __restrict__ Wt, const float* __restrict__ WbT,
    u16* __restrict__ qh, u16* __restrict__ kh, u16* __restrict__ vh,
    float* __restrict__ biasN)
{
    __shared__ __align__(16) char shraw[17408];
    lnmm_body(blockIdx.x, threadIdx.x, shraw, pair, ln_g, ln_b, Wt, WbT, qh, kh, vh, biasN);
}

__global__ __launch_bounds__(256, 4) void k_attn(
    u16* __restrict__ qh, const u16* __restrict__ kh, const u16* __restrict__ vh,
    const float* __restrict__ biasN)
{
    __shared__ __align__(16) char shraw[22016];
    attn_body(blockIdx.x, threadIdx.x, shraw, qh, kh, vh, biasN);
}

__global__ __launch_bounds__(256) void k_out(
    const u16* __restrict__ aoh, const float* __restrict__ pair,
    const u16* __restrict__ Wt, const float* __restrict__ bo,
    const float* __restrict__ bg, float* __restrict__ out)
{
    out_body(blockIdx.x, threadIdx.x, aoh, pair, Wt, bo, bg, out);
}

// ---------------------------------------------------------------------------
// Workspace (~51.5 MB):
//   [0, 1.0 MB)    biasN fp32 [H][j][k]   (natural layout, LOG2E-scaled)
//   [+,  +16.8MB)  qh bf16 [H][NP][32]    (Q in, O out in place)
//   [+,  +16.8MB)  kh
//   [+,  +16.8MB)  vh
//   [+,  +160K)    Wt bf16 [5][128][128]
//   [+,  +2K)      WbT fp32 [4][128]
// ---------------------------------------------------------------------------
extern "C" void kernel_launch(void* const* d_in, const int* in_sizes, int n_in,
                              void* d_out, int out_size, void* d_ws, size_t ws_size,
                              hipStream_t stream) {
    const float* pair  = (const float*)d_in[0];
    const float* ln_g  = (const float*)d_in[1];
    const float* ln_b  = (const float*)d_in[2];
    const float* Wq    = (const float*)d_in[3];
    const float* Wk    = (const float*)d_in[4];
    const float* Wv    = (const float*)d_in[5];
    const float* Wbias = (const float*)d_in[6];
    const float* Wo    = (const float*)d_in[7];
    const float* bo    = (const float*)d_in[8];
    const float* Wg    = (const float*)d_in[9];
    const float* bg    = (const float*)d_in[10];
    float* out = (float*)d_out;

    float* biasN = (float*)d_ws;                      // 1.0 MB fp32
    u16* qh = (u16*)(biasN + (size_t)H_ * NP_);
    u16* kh = qh + (size_t)NP_ * C_;
    u16* vh = kh + (size_t)NP_ * C_;
    u16* Wt = vh + (size_t)NP_ * C_;
    float* WbT = (float*)(Wt + 5 * 16384);

    // ---- spill guard: only take the cooperative path if k_fused compiled
    //      with zero scratch and <=128 VGPR (4 blocks/CU feasible). ----
    static int coop_ok = -1;
    if (coop_ok < 0) {
        hipFuncAttributes fa;
        if (hipFuncGetAttributes(&fa, (const void*)k_fused) == hipSuccess
            && fa.localSizeBytes == 0 && fa.numRegs <= 128)
            coop_ok = 1;
        else
            coop_ok = 0;
    }

    hipError_t e = hipErrorUnknown;
    if (coop_ok == 1) {
        void* kargs[] = {
            (void*)&pair, (void*)&ln_g, (void*)&ln_b,
            (void*)&Wq, (void*)&Wk, (void*)&Wv,
            (void*)&Wbias, (void*)&Wo, (void*)&bo,
            (void*)&Wg, (void*)&bg, (void*)&out,
            (void*)&Wt, (void*)&WbT,
            (void*)&qh, (void*)&kh, (void*)&vh, (void*)&biasN
        };
        e = hipLaunchCooperativeKernel((void*)k_fused, dim3(1024), dim3(256),
                                       kargs, 0, stream);
    }
    if (e != hipSuccess) {
        // Fallback: round-3 four-dispatch pipeline (204 us).
        k_prep<<<21, 256, 0, stream>>>(Wq, Wk, Wv, Wo, Wg, Wbias, Wt, WbT);
        k_lnmm<<<NP_ / 64, 256, 0, stream>>>(pair, ln_g, ln_b, Wt, WbT, qh, kh, vh, biasN);
        k_attn<<<L_ * H_, 256, 0, stream>>>(qh, kh, vh, biasN);
        k_out<<<NP_ / 128, 256, 0, stream>>>(qh, pair, Wt, bo, bg, out);
    }
}

// Round 7
// 201.120 us; speedup vs baseline: 5.1795x; 1.0059x over previous
//
#include <hip/hip_runtime.h>
#include <hip/hip_cooperative_groups.h>
#include <cstdint>
#include <cstddef>

namespace cg = cooperative_groups;

#define L_ 256
#define C_ 128
#define H_ 4
#define D_ 32
#define NP_ (L_ * L_)

typedef unsigned short u16;
typedef uint32_t u32;
typedef __attribute__((ext_vector_type(8))) short bf16x8;   // 4 VGPRs: MFMA A/B frag
typedef __attribute__((ext_vector_type(4))) float f32x4;    // MFMA C/D frag

__device__ __forceinline__ float bflo(u32 u) { union { u32 i; float f; } v; v.i = u << 16; return v.f; }
__device__ __forceinline__ float bfhi(u32 u) { union { u32 i; float f; } v; v.i = u & 0xffff0000u; return v.f; }
__device__ __forceinline__ u16 f2b(float f) {
    u32 x = __float_as_uint(f);
    return (u16)((x + 0x7fffu + ((x >> 16) & 1u)) >> 16);
}
__device__ __forceinline__ u32 pk2(float lo, float hi) {
    return ((u32)f2b(hi) << 16) | (u32)f2b(lo);
}
__device__ __forceinline__ bf16x8 pack8(float4 a, float4 b) {
    union { u32 u[4]; bf16x8 v; } r;
    r.u[0] = pk2(a.x, a.y); r.u[1] = pk2(a.z, a.w);
    r.u[2] = pk2(b.x, b.y); r.u[3] = pk2(b.z, b.w);
    return r.v;
}

// ===========================================================================
// Round-7 plan: fused cooperative kernel, but phase 1 uses the 32-ROW lnmm
// body (round-4 verified: same speed, VGPR 48 vs 116). Round-6's guard
// tripped because the 64-row body pushed the fused kernel past the 128-VGPR
// / zero-spill budget under waves_per_eu(4,4). With the 32-row body the max
// phase is attn (~100 VGPR) -> guard should pass. Fallback = round-3
// pipeline verbatim (202-204 us floor).
// ===========================================================================

// ---- Phase 0: weight prep (vb 0..20) ----
__device__ __forceinline__ void prep_body(
    int b, int t, char* shraw,
    const float* __restrict__ Wq, const float* __restrict__ Wk, const float* __restrict__ Wv,
    const float* __restrict__ Wo, const float* __restrict__ Wg,
    const float* __restrict__ Wbias, u16* __restrict__ Wt, float* __restrict__ WbT)
{
    auto tile = reinterpret_cast<float(*)[65]>(shraw);   // [64][65] = 16640 B
    if (b < 20) {
        const int mat = b >> 2, tl = b & 3, tr = tl >> 1, tc = tl & 1;
        const float* W = (mat == 0) ? Wq : (mat == 1) ? Wk : (mat == 2) ? Wv : (mat == 3) ? Wo : Wg;
        // mat 0: 1/sqrt(32) * log2(e)  (exp2 path downstream)
        const float s = (mat == 0) ? 0.2550680544705824f : 1.f;
        const int rlo = t >> 6, col = t & 63;
        #pragma unroll
        for (int m = 0; m < 16; ++m) {
            int row = m * 4 + rlo;
            tile[row][col] = W[(size_t)(tr * 64 + row) * C_ + tc * 64 + col];
        }
        __syncthreads();
        #pragma unroll
        for (int m = 0; m < 16; ++m) {
            int n = tc * 64 + m * 4 + rlo;
            int c = tr * 64 + col;
            Wt[mat * 16384 + n * C_ + c] = f2b(tile[col][m * 4 + rlo] * s);
        }
    } else {
        #pragma unroll
        for (int m = 0; m < 2; ++m) {
            int idx = m * 256 + t;
            int h = idx >> 7, c = idx & 127;
            WbT[h * C_ + c] = Wbias[c * H_ + h] * 1.4426950408889634f;
        }
    }
}

// ---- Phase 1 (fused path): 32-row LN + QKV + bias (vb 0..2047) ----
// Round-4 verified body: VGPR 48 standalone, same speed as 64-row.
__device__ __forceinline__ void lnmm32_body(
    int vb, int t, char* shraw,
    const float* __restrict__ pair, const float* __restrict__ ln_g, const float* __restrict__ ln_b,
    const u16* __restrict__ Wt, const float* __restrict__ WbT,
    u16* __restrict__ qh, u16* __restrict__ kh, u16* __restrict__ vh,
    float* __restrict__ biasN)
{
    auto zsh = reinterpret_cast<u16(*)[136]>(shraw);   // [32][136] = 8704 B

    const int p0 = vb * 32;
    const int row = t >> 3, seg = t & 7;   // 8 lanes/row, 32 rows

    float4 xv[4];
    float sum = 0.f, ss = 0.f;
    #pragma unroll
    for (int i = 0; i < 4; ++i) {
        int c = (seg + 8 * i) * 4;
        float4 x = *(const float4*)(pair + (size_t)(p0 + row) * C_ + c);
        xv[i] = x;
        sum += x.x + x.y + x.z + x.w;
        ss  += x.x * x.x + x.y * x.y + x.z * x.z + x.w * x.w;
    }
    sum += __shfl_xor(sum, 1); sum += __shfl_xor(sum, 2); sum += __shfl_xor(sum, 4);
    ss  += __shfl_xor(ss, 1);  ss  += __shfl_xor(ss, 2);  ss  += __shfl_xor(ss, 4);
    float mu  = sum * (1.0f / C_);
    float var = ss * (1.0f / C_) - mu * mu;
    float rs  = rsqrtf(fmaxf(var, 0.f) + 1e-5f);

    #pragma unroll
    for (int i = 0; i < 4; ++i) {
        int c = (seg + 8 * i) * 4;
        float4 g4 = *(const float4*)(ln_g + c);
        float4 b4 = *(const float4*)(ln_b + c);
        float4 x  = xv[i];
        float z0 = (x.x - mu) * rs * g4.x + b4.x;
        float z1 = (x.y - mu) * rs * g4.y + b4.y;
        float z2 = (x.z - mu) * rs * g4.z + b4.z;
        float z3 = (x.w - mu) * rs * g4.w + b4.w;
        *(u32*)&zsh[row][c]     = pk2(z0, z1);
        *(u32*)&zsh[row][c + 2] = pk2(z2, z3);
    }
    __syncthreads();

    const int w    = t >> 6;
    const int l15  = t & 15;
    const int quad = (t >> 4) & 3;

    bf16x8 zf[2][4];
    #pragma unroll
    for (int jt = 0; jt < 2; ++jt)
        #pragma unroll
        for (int kc = 0; kc < 4; ++kc)
            zf[jt][kc] = *(const bf16x8*)&zsh[jt * 16 + l15][kc * 32 + quad * 8];

    #pragma unroll
    for (int k = 0; k < 6; ++k) {
        const int tt = w * 6 + k;
        const int mat = tt >> 3, mt = tt & 7;
        f32x4 acc0 = {0.f,0.f,0.f,0.f}, acc1 = acc0;
        #pragma unroll
        for (int kc = 0; kc < 4; ++kc) {
            bf16x8 af = *(const bf16x8*)(Wt + (size_t)tt * 2048 + (size_t)l15 * 128 + kc * 32 + quad * 8);
            acc0 = __builtin_amdgcn_mfma_f32_16x16x32_bf16(af, zf[0][kc], acc0, 0, 0, 0);
            acc1 = __builtin_amdgcn_mfma_f32_16x16x32_bf16(af, zf[1][kc], acc1, 0, 0, 0);
        }
        u16* dst = (mat == 0) ? qh : (mat == 1) ? kh : vh;
        const int hh = mt >> 1;
        const int cb = (mt & 1) * 16 + quad * 4;
        f32x4 accs[2] = {acc0, acc1};
        #pragma unroll
        for (int jt = 0; jt < 2; ++jt) {
            const int p = p0 + jt * 16 + l15;
            *(uint2*)(dst + ((size_t)hh * NP_ + p) * D_ + cb) =
                make_uint2(pk2(accs[jt][0], accs[jt][1]), pk2(accs[jt][2], accs[jt][3]));
        }
    }

    if (t < 128) {
        const int row2 = t >> 2, seg2 = t & 3;
        float a = 0.f;
        #pragma unroll
        for (int c8 = 0; c8 < C_; c8 += 8) {
            uint4 zz = *(const uint4*)&zsh[row2][c8];
            float4 wb0 = *(const float4*)(WbT + seg2 * C_ + c8);
            float4 wb1 = *(const float4*)(WbT + seg2 * C_ + c8 + 4);
            a += bflo(zz.x) * wb0.x + bfhi(zz.x) * wb0.y
               + bflo(zz.y) * wb0.z + bfhi(zz.y) * wb0.w
               + bflo(zz.z) * wb1.x + bfhi(zz.z) * wb1.y
               + bflo(zz.w) * wb1.z + bfhi(zz.w) * wb1.w;
        }
        const int p = p0 + row2;
        biasN[(size_t)seg2 * NP_ + p] = a;
    }
}

// ---- Phase 1 (fallback path): 64-row LN body, round-3 verbatim ----
__device__ __forceinline__ void lnmm_body(
    int vb, int t, char* shraw,
    const float* __restrict__ pair, const float* __restrict__ ln_g, const float* __restrict__ ln_b,
    const u16* __restrict__ Wt, const float* __restrict__ WbT,
    u16* __restrict__ qh, u16* __restrict__ kh, u16* __restrict__ vh,
    float* __restrict__ biasN)
{
    auto zsh = reinterpret_cast<u16(*)[136]>(shraw);   // [64][136] = 17408 B

    const int p0 = vb * 64;
    const int row = t >> 2, seg = t & 3;

    float4 xv[8];
    float sum = 0.f, ss = 0.f;
    #pragma unroll
    for (int i = 0; i < 8; ++i) {
        int c = (seg + 4 * i) * 4;
        float4 x = *(const float4*)(pair + (size_t)(p0 + row) * C_ + c);
        xv[i] = x;
        sum += x.x + x.y + x.z + x.w;
        ss  += x.x * x.x + x.y * x.y + x.z * x.z + x.w * x.w;
    }
    sum += __shfl_xor(sum, 1); sum += __shfl_xor(sum, 2);
    ss  += __shfl_xor(ss, 1);  ss  += __shfl_xor(ss, 2);
    float mu  = sum * (1.0f / C_);
    float var = ss * (1.0f / C_) - mu * mu;
    float rs  = rsqrtf(fmaxf(var, 0.f) + 1e-5f);

    #pragma unroll
    for (int i = 0; i < 8; ++i) {
        int c = (seg + 4 * i) * 4;
        float4 g4 = *(const float4*)(ln_g + c);
        float4 b4 = *(const float4*)(ln_b + c);
        float4 x  = xv[i];
        float z0 = (x.x - mu) * rs * g4.x + b4.x;
        float z1 = (x.y - mu) * rs * g4.y + b4.y;
        float z2 = (x.z - mu) * rs * g4.z + b4.z;
        float z3 = (x.w - mu) * rs * g4.w + b4.w;
        *(u32*)&zsh[row][c]     = pk2(z0, z1);
        *(u32*)&zsh[row][c + 2] = pk2(z2, z3);
    }
    __syncthreads();

    const int w    = t >> 6;
    const int l15  = t & 15;
    const int quad = (t >> 4) & 3;

    bf16x8 zf[4][4];
    #pragma unroll
    for (int jt = 0; jt < 4; ++jt)
        #pragma unroll
        for (int kc = 0; kc < 4; ++kc)
            zf[jt][kc] = *(const bf16x8*)&zsh[jt * 16 + l15][kc * 32 + quad * 8];

    #pragma unroll
    for (int k = 0; k < 6; ++k) {
        const int tt = w * 6 + k;
        const int mat = tt >> 3, mt = tt & 7;
        f32x4 acc0 = {0.f,0.f,0.f,0.f}, acc1 = acc0, acc2 = acc0, acc3 = acc0;
        #pragma unroll
        for (int kc = 0; kc < 4; ++kc) {
            bf16x8 af = *(const bf16x8*)(Wt + (size_t)tt * 2048 + (size_t)l15 * 128 + kc * 32 + quad * 8);
            acc0 = __builtin_amdgcn_mfma_f32_16x16x32_bf16(af, zf[0][kc], acc0, 0, 0, 0);
            acc1 = __builtin_amdgcn_mfma_f32_16x16x32_bf16(af, zf[1][kc], acc1, 0, 0, 0);
            acc2 = __builtin_amdgcn_mfma_f32_16x16x32_bf16(af, zf[2][kc], acc2, 0, 0, 0);
            acc3 = __builtin_amdgcn_mfma_f32_16x16x32_bf16(af, zf[3][kc], acc3, 0, 0, 0);
        }
        u16* dst = (mat == 0) ? qh : (mat == 1) ? kh : vh;
        const int hh = mt >> 1;
        const int cb = (mt & 1) * 16 + quad * 4;
        f32x4 accs[4] = {acc0, acc1, acc2, acc3};
        #pragma unroll
        for (int jt = 0; jt < 4; ++jt) {
            const int p = p0 + jt * 16 + l15;
            *(uint2*)(dst + ((size_t)hh * NP_ + p) * D_ + cb) =
                make_uint2(pk2(accs[jt][0], accs[jt][1]), pk2(accs[jt][2], accs[jt][3]));
        }
    }

    {
        float a = 0.f;
        #pragma unroll
        for (int c8 = 0; c8 < C_; c8 += 8) {
            uint4 zz = *(const uint4*)&zsh[row][c8];
            float4 wb0 = *(const float4*)(WbT + seg * C_ + c8);
            float4 wb1 = *(const float4*)(WbT + seg * C_ + c8 + 4);
            a += bflo(zz.x) * wb0.x + bfhi(zz.x) * wb0.y
               + bflo(zz.y) * wb0.z + bfhi(zz.y) * wb0.w
               + bflo(zz.z) * wb1.x + bfhi(zz.z) * wb1.y
               + bflo(zz.w) * wb1.z + bfhi(zz.w) * wb1.w;
        }
        const int p = p0 + row;
        biasN[(size_t)seg * NP_ + p] = a;
    }
}

// ---- Phase 2: attention (vb 0..1023 = (i,h)) ----
__device__ __forceinline__ void attn_body(
    int vb, int t, char* shraw,
    u16* __restrict__ qh, const u16* __restrict__ kh, const u16* __restrict__ vh,
    const float* __restrict__ biasN)
{
    u16* Vsh = reinterpret_cast<u16*>(shraw);                       // D_*264*2 = 16896 B
    auto Psh = reinterpret_cast<u16(*)[16][40]>(shraw + 16896);     // 4*16*40*2 = 5120 B

    const int i = vb >> 2;
    const int h = vb & 3;
    const int w    = t >> 6;
    const int l15  = t & 15;
    const int quad = (t >> 4) & 3;
    const int jbase = w * 64;

    const u16* Kg = kh + ((size_t)h * NP_ + i * L_) * D_;
    const u16* Vg = vh + ((size_t)h * NP_ + i * L_) * D_;
    u16*       Qg = qh + ((size_t)h * NP_ + i * L_) * D_;

    #pragma unroll
    for (int jj = 0; jj < 4; ++jj) {
        int idx = t + jj * 256;
        int r = idx >> 2, sg = idx & 3;
        union { uint4 q; u16 s[8]; } u;
        u.q = *(const uint4*)(Vg + r * D_ + sg * 8);
        #pragma unroll
        for (int m = 0; m < 8; ++m) Vsh[(sg * 8 + m) * 264 + r] = u.s[m];
    }

    bf16x8 qf[4];
    #pragma unroll
    for (int jt = 0; jt < 4; ++jt)
        qf[jt] = *(const bf16x8*)(Qg + (size_t)(jbase + jt * 16 + l15) * D_ + quad * 8);

    __syncthreads();

    const f32x4 z4 = {0.f, 0.f, 0.f, 0.f};
    f32x4 oacc[4][2], osum[4];
    #pragma unroll
    for (int jt = 0; jt < 4; ++jt) {
        oacc[jt][0] = z4; oacc[jt][1] = z4; osum[jt] = z4;
    }

    bf16x8 onesb;
    { union { u32 u[4]; bf16x8 v; } ob;
      ob.u[0] = ob.u[1] = ob.u[2] = ob.u[3] = 0x3F803F80u; onesb = ob.v; }

    const float* bN = biasN + (size_t)h * NP_;

    bf16x8 kb0 = *(const bf16x8*)(Kg + (size_t)l15 * D_ + quad * 8);
    bf16x8 kb1 = *(const bf16x8*)(Kg + (size_t)(16 + l15) * D_ + quad * 8);

    for (int kc = 0; kc < 8; ++kc) {
        bf16x8 nb0, nb1;
        if (kc < 7) {
            nb0 = *(const bf16x8*)(Kg + (size_t)((kc + 1) * 32 + l15) * D_ + quad * 8);
            nb1 = *(const bf16x8*)(Kg + (size_t)((kc + 1) * 32 + 16 + l15) * D_ + quad * 8);
        }
        bf16x8 vb0 = *(const bf16x8*)&Vsh[l15 * 264 + kc * 32 + quad * 8];
        bf16x8 vb1 = *(const bf16x8*)&Vsh[(16 + l15) * 264 + kc * 32 + quad * 8];

        #pragma unroll
        for (int jt = 0; jt < 4; ++jt) {
            f32x4 s0 = __builtin_amdgcn_mfma_f32_16x16x32_bf16(kb0, qf[jt], z4, 0, 0, 0);
            f32x4 s1 = __builtin_amdgcn_mfma_f32_16x16x32_bf16(kb1, qf[jt], z4, 0, 0, 0);

            const float* bp = bN + (size_t)(jbase + jt * 16 + l15) * L_ + kc * 32 + quad * 4;
            float4 bv0 = *(const float4*)bp;
            float4 bv1 = *(const float4*)(bp + 16);

            float e0[4], e1[4];
            e0[0] = __builtin_amdgcn_exp2f(s0[0] + bv0.x);
            e0[1] = __builtin_amdgcn_exp2f(s0[1] + bv0.y);
            e0[2] = __builtin_amdgcn_exp2f(s0[2] + bv0.z);
            e0[3] = __builtin_amdgcn_exp2f(s0[3] + bv0.w);
            e1[0] = __builtin_amdgcn_exp2f(s1[0] + bv1.x);
            e1[1] = __builtin_amdgcn_exp2f(s1[1] + bv1.y);
            e1[2] = __builtin_amdgcn_exp2f(s1[2] + bv1.z);
            e1[3] = __builtin_amdgcn_exp2f(s1[3] + bv1.w);

            u32 w0, w1, w2, w3;
            asm("v_cvt_pk_bf16_f32 %0, %1, %2" : "=v"(w0) : "v"(e0[0]), "v"(e0[1]));
            asm("v_cvt_pk_bf16_f32 %0, %1, %2" : "=v"(w1) : "v"(e0[2]), "v"(e0[3]));
            asm("v_cvt_pk_bf16_f32 %0, %1, %2" : "=v"(w2) : "v"(e1[0]), "v"(e1[1]));
            asm("v_cvt_pk_bf16_f32 %0, %1, %2" : "=v"(w3) : "v"(e1[2]), "v"(e1[3]));
            *(uint2*)&Psh[w][l15][quad * 4]      = make_uint2(w0, w1);
            *(uint2*)&Psh[w][l15][16 + quad * 4] = make_uint2(w2, w3);

            bf16x8 pa = *(const bf16x8*)&Psh[w][l15][quad * 8];
            oacc[jt][0] = __builtin_amdgcn_mfma_f32_16x16x32_bf16(pa, vb0,   oacc[jt][0], 0, 0, 0);
            oacc[jt][1] = __builtin_amdgcn_mfma_f32_16x16x32_bf16(pa, vb1,   oacc[jt][1], 0, 0, 0);
            osum[jt]    = __builtin_amdgcn_mfma_f32_16x16x32_bf16(pa, onesb, osum[jt],    0, 0, 0);
        }
        kb0 = nb0; kb1 = nb1;
    }

    #pragma unroll
    for (int jt = 0; jt < 4; ++jt) {
        #pragma unroll
        for (int r = 0; r < 4; ++r) {
            float rn = 1.f / osum[jt][r];
            size_t rowo = (size_t)(jbase + jt * 16 + quad * 4 + r) * D_;
            Qg[rowo + l15]      = f2b(oacc[jt][0][r] * rn);
            Qg[rowo + 16 + l15] = f2b(oacc[jt][1][r] * rn);
        }
    }
}

// ---- Phase 3: output projection + gate (vb 0..511, 128 rows) ----
__device__ __forceinline__ void out_body(
    int vb, int t,
    const u16* __restrict__ aoh, const float* __restrict__ pair,
    const u16* __restrict__ Wt, const float* __restrict__ bo,
    const float* __restrict__ bg, float* __restrict__ out)
{
    const int p0 = vb * 128;
    const int w    = t >> 6;
    const int l15  = t & 15;
    const int quad = (t >> 4) & 3;

    bf16x8 aof[2][4], pf[2][4];
    int prow[2];
    #pragma unroll
    for (int g = 0; g < 2; ++g) {
        prow[g] = p0 + w * 32 + g * 16 + l15;
        #pragma unroll
        for (int kc = 0; kc < 4; ++kc) {
            aof[g][kc] = *(const bf16x8*)(aoh + ((size_t)kc * NP_ + prow[g]) * D_ + quad * 8);
            const float* pp = pair + (size_t)prow[g] * C_ + kc * 32 + quad * 8;
            pf[g][kc] = pack8(*(const float4*)pp, *(const float4*)(pp + 4));
        }
    }

    const u16* WoT = Wt + 3 * 16384;
    const u16* WgT = Wt + 4 * 16384;

    #pragma unroll
    for (int nt = 0; nt < 8; ++nt) {
        f32x4 accO0 = {0.f,0.f,0.f,0.f}, accO1 = accO0, accG0 = accO0, accG1 = accO0;
        #pragma unroll
        for (int kc = 0; kc < 4; ++kc) {
            bf16x8 awo = *(const bf16x8*)(WoT + (size_t)(nt * 16 + l15) * 128 + kc * 32 + quad * 8);
            bf16x8 awg = *(const bf16x8*)(WgT + (size_t)(nt * 16 + l15) * 128 + kc * 32 + quad * 8);
            accO0 = __builtin_amdgcn_mfma_f32_16x16x32_bf16(awo, aof[0][kc], accO0, 0, 0, 0);
            accO1 = __builtin_amdgcn_mfma_f32_16x16x32_bf16(awo, aof[1][kc], accO1, 0, 0, 0);
            accG0 = __builtin_amdgcn_mfma_f32_16x16x32_bf16(awg, pf[0][kc],  accG0, 0, 0, 0);
            accG1 = __builtin_amdgcn_mfma_f32_16x16x32_bf16(awg, pf[1][kc],  accG1, 0, 0, 0);
        }
        const int ch = nt * 16 + quad * 4;
        float4 bo4 = *(const float4*)(bo + ch);
        float4 bg4 = *(const float4*)(bg + ch);
        f32x4 aO[2] = {accO0, accO1}, aG[2] = {accG0, accG1};
        #pragma unroll
        for (int g = 0; g < 2; ++g) {
            float4 pr = *(const float4*)(pair + (size_t)prow[g] * C_ + ch);
            float4 r;
            r.x = pr.x + (1.f / (1.f + __expf(-(aG[g][0] + bg4.x)))) * (aO[g][0] + bo4.x);
            r.y = pr.y + (1.f / (1.f + __expf(-(aG[g][1] + bg4.y)))) * (aO[g][1] + bo4.y);
            r.z = pr.z + (1.f / (1.f + __expf(-(aG[g][2] + bg4.z)))) * (aO[g][2] + bo4.z);
            r.w = pr.w + (1.f / (1.f + __expf(-(aG[g][3] + bg4.w)))) * (aO[g][3] + bo4.w);
            *(float4*)(out + (size_t)prow[g] * C_ + ch) = r;
        }
    }
}

// ===========================================================================
// Fused cooperative kernel: waves_per_eu(4,4) pins the allocator at the full
// 128-VGPR budget; phase 1 = 32-row lnmm (VGPR 48 standalone) so the max
// phase (attn ~100) fits without spills. Grid 1024 = 4 blocks/CU.
// ===========================================================================
__global__ __launch_bounds__(256)
__attribute__((amdgpu_waves_per_eu(4, 4)))
void k_fused(
    const float* __restrict__ pair, const float* __restrict__ ln_g, const float* __restrict__ ln_b,
    const float* __restrict__ Wq, const float* __restrict__ Wk, const float* __restrict__ Wv,
    const float* __restrict__ Wbias, const float* __restrict__ Wo, const float* __restrict__ bo,
    const float* __restrict__ Wg, const float* __restrict__ bg, float* __restrict__ out,
    u16* __restrict__ Wt, float* __restrict__ WbT,
    u16* __restrict__ qh, u16* __restrict__ kh, u16* __restrict__ vh, float* __restrict__ biasN)
{
    __shared__ __align__(16) char shraw[22016];
    cg::grid_group grid = cg::this_grid();
    const int t = threadIdx.x;

    // Phase 0: prep
    for (int vb = blockIdx.x; vb < 21; vb += gridDim.x)
        prep_body(vb, t, shraw, Wq, Wk, Wv, Wo, Wg, Wbias, Wt, WbT);
    __threadfence();
    grid.sync();

    // Phase 1: LN + QKV + bias (32-row body, 2048 vbs -> 2 per block)
    for (int vb = blockIdx.x; vb < 2048; vb += gridDim.x) {
        lnmm32_body(vb, t, shraw, pair, ln_g, ln_b, Wt, WbT, qh, kh, vh, biasN);
        __syncthreads();   // protect shared zsh across grid-stride iterations
    }
    __threadfence();
    grid.sync();

    // Phase 2: attention (O written in place of Q)
    for (int vb = blockIdx.x; vb < 1024; vb += gridDim.x)
        attn_body(vb, t, shraw, qh, kh, vh, biasN);
    __threadfence();
    grid.sync();

    // Phase 3: out projection + gate
    for (int vb = blockIdx.x; vb < 512; vb += gridDim.x)
        out_body(vb, t, qh, pair, Wt, bo, bg, out);
}

// ===========================================================================
// Fallback standalone kernels (round-3 exact, 202-204 us total), used if the
// fused kernel spills (hipFuncGetAttributes guard) or cooperative launch is
// rejected.
// ===========================================================================
__global__ __launch_bounds__(256) void k_prep(
    const float* __restrict__ Wq, const float* __restrict__ Wk, const float* __restrict__ Wv,
    const float* __restrict__ Wo, const float* __restrict__ Wg,
    const float* __restrict__ Wbias, u16* __restrict__ Wt, float* __restrict__ WbT)
{
    __shared__ __align__(16) char shraw[16640];
    prep_body(blockIdx.x, threadIdx.x, shraw, Wq, Wk, Wv, Wo, Wg, Wbias, Wt, WbT);
}

__global__ __launch_bounds__(256) void k_lnmm(
    const float* __restrict__ pair, const float* __restrict__ ln_g, const float* __restrict__ ln_b,
    const u16* __restrict__ Wt, const float* __restrict__ WbT,
    u16* __restrict__ qh, u16* __restrict__ kh, u16* __restrict__ vh,
    float* __restrict__ biasN)
{
    __shared__ __align__(16) char shraw[17408];
    lnmm_body(blockIdx.x, threadIdx.x, shraw, pair, ln_g, ln_b, Wt, WbT, qh, kh, vh, biasN);
}

__global__ __launch_bounds__(256, 4) void k_attn(
    u16* __restrict__ qh, const u16* __restrict__ kh, const u16* __restrict__ vh,
    const float* __restrict__ biasN)
{
    __shared__ __align__(16) char shraw[22016];
    attn_body(blockIdx.x, threadIdx.x, shraw, qh, kh, vh, biasN);
}

__global__ __launch_bounds__(256) void k_out(
    const u16* __restrict__ aoh, const float* __restrict__ pair,
    const u16* __restrict__ Wt, const float* __restrict__ bo,
    const float* __restrict__ bg, float* __restrict__ out)
{
    out_body(blockIdx.x, threadIdx.x, aoh, pair, Wt, bo, bg, out);
}

// ---------------------------------------------------------------------------
// Workspace (~51.5 MB):
//   [0, 1.0 MB)    biasN fp32 [H][j][k]   (natural layout, LOG2E-scaled)
//   [+,  +16.8MB)  qh bf16 [H][NP][32]    (Q in, O out in place)
//   [+,  +16.8MB)  kh
//   [+,  +16.8MB)  vh
//   [+,  +160K)    Wt bf16 [5][128][128]
//   [+,  +2K)      WbT fp32 [4][128]
// ---------------------------------------------------------------------------
extern "C" void kernel_launch(void* const* d_in, const int* in_sizes, int n_in,
                              void* d_out, int out_size, void* d_ws, size_t ws_size,
                              hipStream_t stream) {
    const float* pair  = (const float*)d_in[0];
    const float* ln_g  = (const float*)d_in[1];
    const float* ln_b  = (const float*)d_in[2];
    const float* Wq    = (const float*)d_in[3];
    const float* Wk    = (const float*)d_in[4];
    const float* Wv    = (const float*)d_in[5];
    const float* Wbias = (const float*)d_in[6];
    const float* Wo    = (const float*)d_in[7];
    const float* bo    = (const float*)d_in[8];
    const float* Wg    = (const float*)d_in[9];
    const float* bg    = (const float*)d_in[10];
    float* out = (float*)d_out;

    float* biasN = (float*)d_ws;                      // 1.0 MB fp32
    u16* qh = (u16*)(biasN + (size_t)H_ * NP_);
    u16* kh = qh + (size_t)NP_ * C_;
    u16* vh = kh + (size_t)NP_ * C_;
    u16* Wt = vh + (size_t)NP_ * C_;
    float* WbT = (float*)(Wt + 5 * 16384);

    // ---- spill guard: only take the cooperative path if k_fused compiled
    //      with zero scratch and <=128 VGPR (4 blocks/CU feasible). ----
    static int coop_ok = -1;
    if (coop_ok < 0) {
        hipFuncAttributes fa;
        if (hipFuncGetAttributes(&fa, (const void*)k_fused) == hipSuccess
            && fa.localSizeBytes == 0 && fa.numRegs <= 128)
            coop_ok = 1;
        else
            coop_ok = 0;
    }

    hipError_t e = hipErrorUnknown;
    if (coop_ok == 1) {
        void* kargs[] = {
            (void*)&pair, (void*)&ln_g, (void*)&ln_b,
            (void*)&Wq, (void*)&Wk, (void*)&Wv,
            (void*)&Wbias, (void*)&Wo, (void*)&bo,
            (void*)&Wg, (void*)&bg, (void*)&out,
            (void*)&Wt, (void*)&WbT,
            (void*)&qh, (void*)&kh, (void*)&vh, (void*)&biasN
        };
        e = hipLaunchCooperativeKernel((void*)k_fused, dim3(1024), dim3(256),
                                       kargs, 0, stream);
    }
    if (e != hipSuccess) {
        // Fallback: round-3 four-dispatch pipeline (202-204 us).
        k_prep<<<21, 256, 0, stream>>>(Wq, Wk, Wv, Wo, Wg, Wbias, Wt, WbT);
        k_lnmm<<<NP_ / 64, 256, 0, stream>>>(pair, ln_g, ln_b, Wt, WbT, qh, kh, vh, biasN);
        k_attn<<<L_ * H_, 256, 0, stream>>>(qh, kh, vh, biasN);
        k_out<<<NP_ / 128, 256, 0, stream>>>(qh, pair, Wt, bo, bg, out);
    }
}